// Round 1
// baseline (28041.528 us; speedup 1.0000x reference)
//
#include <hip/hip_runtime.h>
#include <math.h>

// Problem constants (match reference)
#define B_    64
#define T_    2048
#define DIN   256
#define DH    256
#define DC    256
#define DOUT  256
#define K2    512   // DIN + DH

__device__ __forceinline__ float sigmoidf_(float x) {
    return 1.0f / (1.0f + __expf(-x));
}

__device__ __forceinline__ float tanhf_(float x) {
    // numerically stable fast tanh
    float ax = fabsf(x);
    float e  = __expf(-2.0f * ax);
    float t  = (1.0f - e) / (1.0f + e);
    return copysignf(t, x);
}

// One workgroup per batch element (64 WGs, 256 threads).
// Thread layout: sl = tid>>6 (k-slice == wave id), cg = (tid&63)*4 (4 adjacent
// output columns -> float4-coalesced weight loads: 64 lanes x 16B = 1KiB/instr).
__global__ __launch_bounds__(256) void lstm_persistent(
    const float* __restrict__ x,    const float* __restrict__ h0,
    const float* __restrict__ c0,   const float* __restrict__ Wf,
    const float* __restrict__ bf,   const float* __restrict__ Wi,
    const float* __restrict__ bi,   const float* __restrict__ Wo,
    const float* __restrict__ bo,   const float* __restrict__ Wout,
    const float* __restrict__ bout, const int* __restrict__ Np,
    float* __restrict__ out)
{
    const int b   = blockIdx.x;
    const int tid = threadIdx.x;
    const int sl  = tid >> 6;         // k-slice 0..3
    const int cg  = (tid & 63) * 4;   // column base: 0,4,...,252
    const int N   = *Np;

    __shared__ float comb[K2];          // [ x_t (256) | h_t (256) ]
    __shared__ float part[3][4][DC];    // [gate][slice][column] partials, 12 KiB

    // init state: thread tid owns cell/hidden column tid
    float c     = c0[b * DC + tid];
    float h_reg = h0[b * DH + tid];
    comb[DIN + tid] = h_reg;
    comb[tid]       = x[((size_t)b * T_ + 0) * DIN + tid];
    __syncthreads();

    const size_t xbase = (size_t)b * T_ * DIN;

    for (int t = 0; t < N; ++t) {
        // ---- gate partial dot-products over k in [sl*128, sl*128+128) ----
        float4 af = {0,0,0,0}, ai = {0,0,0,0}, ao = {0,0,0,0};
        const int k0 = sl * 128;
        #pragma unroll 4
        for (int k = k0; k < k0 + 128; ++k) {
            const float ck = comb[k];   // wave-uniform LDS broadcast
            const float4 wf = *(const float4*)(Wf + (size_t)k * DC + cg);
            const float4 wi = *(const float4*)(Wi + (size_t)k * DC + cg);
            const float4 wo = *(const float4*)(Wo + (size_t)k * DC + cg);
            af.x += ck * wf.x; af.y += ck * wf.y; af.z += ck * wf.z; af.w += ck * wf.w;
            ai.x += ck * wi.x; ai.y += ck * wi.y; ai.z += ck * wi.z; ai.w += ck * wi.w;
            ao.x += ck * wo.x; ao.y += ck * wo.y; ao.z += ck * wo.z; ao.w += ck * wo.w;
        }
        *(float4*)&part[0][sl][cg] = af;
        *(float4*)&part[1][sl][cg] = ai;
        *(float4*)&part[2][sl][cg] = ao;
        __syncthreads();

        // ---- per-column gate math (thread tid owns column tid) ----
        const int n = tid;
        float fp = bf[n] + part[0][0][n] + part[0][1][n] + part[0][2][n] + part[0][3][n];
        float ip = bi[n] + part[1][0][n] + part[1][1][n] + part[1][2][n] + part[1][3][n];
        float op = bo[n] + part[2][0][n] + part[2][1][n] + part[2][2][n] + part[2][3][n];
        const float f = sigmoidf_(fp);
        const float i = sigmoidf_(ip);
        const float z = tanhf_(ip);      // pre_i reused for tanh per reference
        const float o = sigmoidf_(op);
        c     = c * f + z * i;
        h_reg = tanhf_(c) * o;
        __syncthreads();                 // all reads of comb/part complete

        comb[DIN + n] = h_reg;                                   // publish h_{t+1}
        if (t + 1 < N) comb[n] = x[xbase + (size_t)(t + 1) * DIN + n]; // next x row
        __syncthreads();

        // ---- output projection: K=256 over 4 slices of 64 ----
        float4 aq = {0,0,0,0};
        const int q0 = sl * 64;
        #pragma unroll 4
        for (int k = q0; k < q0 + 64; ++k) {
            const float hk = comb[DIN + k];
            const float4 w = *(const float4*)(Wout + (size_t)k * DOUT + cg);
            aq.x += hk * w.x; aq.y += hk * w.y; aq.z += hk * w.z; aq.w += hk * w.w;
        }
        *(float4*)&part[0][sl][cg] = aq;
        __syncthreads();
        const float q = bout[n] + part[0][0][n] + part[0][1][n]
                                + part[0][2][n] + part[0][3][n];
        out[((size_t)b * N + t) * DOUT + n] = sigmoidf_(q);
        __syncthreads();                 // protect part[] before next iteration
    }

    // finals: d_out = [ outs (B*N*DOUT) | h_final (B*DH) | c_final (B*DC) ]
    float* hf = out + (size_t)B_ * N * DOUT;
    float* cf = hf + (size_t)B_ * DH;
    hf[b * DH + tid] = h_reg;
    cf[b * DC + tid] = c;
}

extern "C" void kernel_launch(void* const* d_in, const int* in_sizes, int n_in,
                              void* d_out, int out_size, void* d_ws, size_t ws_size,
                              hipStream_t stream) {
    const float* x    = (const float*)d_in[0];
    const float* h0   = (const float*)d_in[1];
    const float* c0   = (const float*)d_in[2];
    const float* Wf   = (const float*)d_in[3];
    const float* bf   = (const float*)d_in[4];
    const float* Wi   = (const float*)d_in[5];
    const float* bi   = (const float*)d_in[6];
    const float* Wo   = (const float*)d_in[7];
    const float* bo   = (const float*)d_in[8];
    const float* Wout = (const float*)d_in[9];
    const float* bout = (const float*)d_in[10];
    const int*   Np   = (const int*)d_in[11];
    float* out = (float*)d_out;

    hipLaunchKernelGGL(lstm_persistent, dim3(B_), dim3(256), 0, stream,
                       x, h0, c0, Wf, bf, Wi, bi, Wo, bo, Wout, bout, Np, out);
}